// Round 11
// baseline (144.643 us; speedup 1.0000x reference)
//
#include <hip/hip_runtime.h>
#include <math.h>

#define NBINS 64
#define HIST_ELEMS (NBINS*NBINS)
#define PTS_PER_BLOCK 3456      // 256 blocks/n * 3456 = 884736 = P; grid 512 = 2/CU even
#define GXN 256                 // blocks per sample
#define TOTAL_HBLOCKS (GXN*2)
#define CHUNKS 27               // per wave: 3456 / (4 waves * 32)
#define LSTRIDE 68              // col-major lh stride (b128 2-way banks = free)
#define NPART 16                // partial histograms (breaks atomic contention 16x)
// weight = exp2(-(u*SQK - b*SQK)^2); SQK = sqrt(8192/63^2*log2(e))
#define SQK 1.7256062f
#define SMEM_FLOATS (2*PTS_PER_BLOCK + NBINS*LSTRIDE)   // 11264 floats = 44 KB

typedef float f4 __attribute__((ext_vector_type(4)));
typedef float f32x4 __attribute__((ext_vector_type(4)));
typedef _Float16 half8 __attribute__((ext_vector_type(8)));
typedef int int4v __attribute__((ext_vector_type(4)));

static __device__ __forceinline__ half8 pack8(const float* w) {
    int4v v;
    v[0] = __builtin_bit_cast(int, __builtin_amdgcn_cvt_pkrtz(w[0], w[1]));
    v[1] = __builtin_bit_cast(int, __builtin_amdgcn_cvt_pkrtz(w[2], w[3]));
    v[2] = __builtin_bit_cast(int, __builtin_amdgcn_cvt_pkrtz(w[4], w[5]));
    v[3] = __builtin_bit_cast(int, __builtin_amdgcn_cvt_pkrtz(w[6], w[7]));
    return __builtin_bit_cast(half8, v);
}

// ws layout (floats): pm[512]: [ (n*2+t)*64 + b ]=block min, [256+...]=block max
//                     @byte 2048: unsigned counter
//                     @byte 4096: float hist_part[NPART][2][4096]  (512 KB, zeroed here)
__global__ __launch_bounds__(256) void minmax_kernel(const float* __restrict__ tar,
                                                     const float* __restrict__ src,
                                                     float* __restrict__ pm,
                                                     unsigned* __restrict__ ctr,
                                                     float* __restrict__ histp, int P) {
    const int b = blockIdx.x, n = blockIdx.y, t = blockIdx.z;
    const f4* x = (const f4*)((t == 0 ? tar : src) + (size_t)n * P);
    const int per = (P / 4) / 64;   // 3456 f4 per block
    float lmin = INFINITY, lmax = -INFINITY;
    for (int i = b * per + threadIdx.x; i < (b + 1) * per; i += 256) {
        f4 v = x[i];
        lmin = fminf(lmin, fminf(fminf(v[0], v[1]), fminf(v[2], v[3])));
        lmax = fmaxf(lmax, fmaxf(fmaxf(v[0], v[1]), fmaxf(v[2], v[3])));
    }
    for (int off = 32; off > 0; off >>= 1) {
        lmin = fminf(lmin, __shfl_down(lmin, off, 64));
        lmax = fmaxf(lmax, __shfl_down(lmax, off, 64));
    }
    __shared__ float smin[4], smax[4];
    const int lane = threadIdx.x & 63, wave = threadIdx.x >> 6;
    if (lane == 0) { smin[wave] = lmin; smax[wave] = lmax; }
    __syncthreads();
    if (threadIdx.x == 0) {
        pm[(n * 2 + t) * 64 + b] =
            fminf(fminf(smin[0], smin[1]), fminf(smin[2], smin[3]));
        pm[256 + (n * 2 + t) * 64 + b] =
            fmaxf(fmaxf(smax[0], smax[1]), fmaxf(smax[2], smax[3]));
    }
    // zero hist_part: NPART*2*4096 = 131072 floats over 256 blocks = 128 f4 each
    const int flat = b + 64 * n + 128 * t;   // 0..255
    f4* hz = (f4*)histp + (size_t)flat * 128;
    const f4 z = {0.f, 0.f, 0.f, 0.f};
    for (int i = threadIdx.x; i < 128; i += 256) hz[i] = z;
    if (flat == 0 && threadIdx.x == 0) *ctr = 0u;
}

// Fused: partial-minmax reduce + MFMA joint-hist (R9 core) + partial-hist
// atomic flush (16 adds/addr, was 256) + last-block reduce+finalize.
// A[m][k]: m=lane&15 (+16*mt), k=quad*8+j ; B[k][n]: n=lane&15, k=quad*8+j
// C/D: col=lane&15, row=quad*4+reg -> col-major lh, serial-wave non-atomic
// combine.  Output hist is TRANSPOSED (loss is transpose-invariant).
__global__ __launch_bounds__(256) void mfma_hist_fused(const float* __restrict__ tar,
                                                       const float* __restrict__ src,
                                                       const float* __restrict__ pm,
                                                       unsigned* __restrict__ ctr,
                                                       float* __restrict__ histp,
                                                       float* __restrict__ out, int P) {
    const int n = blockIdx.y;
    const int bx = blockIdx.x;
    const int tid = threadIdx.x;
    const int lane = tid & 63, wave = tid >> 6;
    const int mlane = lane & 15, quad = lane >> 4;

    __shared__ float smem[SMEM_FLOATS];
    __shared__ float mmred[4];
    __shared__ int lastflag;
    float* su_t = smem;
    float* su_s = smem + PTS_PER_BLOCK;
    float* lh = smem + 2 * PTS_PER_BLOCK;   // col-major: lh[col*LSTRIDE + row]

    // --- wave 0: reduce the 64 per-block minmax partials ---
    if (wave == 0) {
        float a = pm[(n * 2 + 0) * 64 + lane];
        float b = pm[256 + (n * 2 + 0) * 64 + lane];
        float c = pm[(n * 2 + 1) * 64 + lane];
        float d = pm[256 + (n * 2 + 1) * 64 + lane];
        for (int off = 32; off > 0; off >>= 1) {
            a = fminf(a, __shfl_down(a, off, 64));
            b = fmaxf(b, __shfl_down(b, off, 64));
            c = fminf(c, __shfl_down(c, off, 64));
            d = fmaxf(d, __shfl_down(d, off, 64));
        }
        if (lane == 0) { mmred[0] = a; mmred[1] = b; mmred[2] = c; mmred[3] = d; }
    }

    // --- stage raw inputs: 864 f4 per tensor, coalesced ---
    {
        const f4* tg = (const f4*)(tar + (size_t)n * P + (size_t)bx * PTS_PER_BLOCK);
        const f4* sg = (const f4*)(src + (size_t)n * P + (size_t)bx * PTS_PER_BLOCK);
        f4* st4 = (f4*)su_t;
        f4* ss4 = (f4*)su_s;
        #pragma unroll
        for (int k = 0; k < 3; ++k) {
            const int i = tid + k * 256;
            st4[i] = tg[i];
            ss4[i] = sg[i];
        }
        if (tid < 96) {
            const int i = 768 + tid;
            st4[i] = tg[i];
            ss4[i] = sg[i];
        }
    }
    __syncthreads();   // staging + mmred complete

    const float tmin = mmred[0], tmax = mmred[1];
    const float smin = mmred[2], smax = mmred[3];
    const float tk = 63.0f / (tmax - tmin + 1e-10f) * SQK;
    const float sk = 63.0f / (smax - smin + 1e-10f) * SQK;
    float mt2[4], ms2[4];
    #pragma unroll
    for (int mt = 0; mt < 4; ++mt) {
        const float b = SQK * (float)(mlane + 16 * mt);
        mt2[mt] = tmin * tk + b;
        ms2[mt] = smin * sk + b;
    }

    f32x4 acc[4][4];
    #pragma unroll
    for (int a = 0; a < 4; ++a)
        #pragma unroll
        for (int b = 0; b < 4; ++b) acc[a][b] = (f32x4){0.f, 0.f, 0.f, 0.f};

    // --- compute: wave owns 864 points = 27 chunks of K=32, barrier-free ---
    const int kwbase = wave * (32 * CHUNKS) + quad * 8;
    #pragma unroll 3
    for (int c = 0; c < CHUNKS; ++c) {
        const int kbase = kwbase + c * 32;
        const f4* pt4 = (const f4*)&su_t[kbase];
        const f4* ps4 = (const f4*)&su_s[kbase];
        f4 ta = pt4[0], tb = pt4[1];
        f4 sa = ps4[0], sb = ps4[1];
        float xt[8] = {ta[0], ta[1], ta[2], ta[3], tb[0], tb[1], tb[2], tb[3]};
        float xs[8] = {sa[0], sa[1], sa[2], sa[3], sb[0], sb[1], sb[2], sb[3]};

        half8 af[4], bf[4];
        #pragma unroll
        for (int mt = 0; mt < 4; ++mt) {
            float w[8];
            #pragma unroll
            for (int j = 0; j < 8; ++j) {
                float d = fmaf(xt[j], tk, -mt2[mt]);
                w[j] = __builtin_amdgcn_exp2f(-(d * d));
            }
            af[mt] = pack8(w);
        }
        #pragma unroll
        for (int nt = 0; nt < 4; ++nt) {
            float w[8];
            #pragma unroll
            for (int j = 0; j < 8; ++j) {
                float d = fmaf(xs[j], sk, -ms2[nt]);
                w[j] = __builtin_amdgcn_exp2f(-(d * d));
            }
            bf[nt] = pack8(w);
        }
        #pragma unroll
        for (int mt = 0; mt < 4; ++mt)
            #pragma unroll
            for (int nt = 0; nt < 4; ++nt)
                acc[mt][nt] = __builtin_amdgcn_mfma_f32_16x16x32_f16(
                    af[mt], bf[nt], acc[mt][nt], 0, 0, 0);
    }

    // --- serial-wave non-atomic combine into col-major lh ---
    #pragma unroll
    for (int w = 0; w < 4; ++w) {
        if (wave == w) {
            #pragma unroll
            for (int nt = 0; nt < 4; ++nt)
                #pragma unroll
                for (int mt = 0; mt < 4; ++mt) {
                    f4* p = (f4*)&lh[(16 * nt + mlane) * LSTRIDE + 16 * mt + 4 * quad];
                    if (w == 0) {
                        *p = acc[mt][nt];
                    } else {
                        f4 v = *p;
                        v += acc[mt][nt];
                        *p = v;
                    }
                }
        }
        __syncthreads();
    }

    // --- flush tile into partial hist (16 adds/addr instead of 256) ---
    float* gh = histp + (((size_t)(bx & (NPART - 1)) * 2 + n) << 12);
    for (int i = tid; i < HIST_ELEMS; i += 256) {
        const int c = i >> 6, r = i & 63;
        unsafeAtomicAdd(&gh[i], lh[c * LSTRIDE + r]);
    }

    // --- last-block finalize ---
    __threadfence();
    if (tid == 0) {
        unsigned old = atomicAdd(ctr, 1u);
        lastflag = (old == TOTAL_HBLOCKS - 1) ? 1 : 0;
    }
    __syncthreads();
    if (!lastflag) return;
    __threadfence();

    // sum the NPART partials (512 KB, L2-resident) into smem hist[2][4096]
    for (int i = tid; i < 2 * HIST_ELEMS; i += 256) {
        const int nn = i >> 12, e = i & 4095;
        float s = 0.0f;
        #pragma unroll
        for (int p = 0; p < NPART; ++p)
            s += __hip_atomic_load(&histp[(((size_t)p * 2 + nn) << 12) + e],
                                   __ATOMIC_RELAXED, __HIP_MEMORY_SCOPE_AGENT);
        smem[i] = s;
    }
    __syncthreads();

    float* buf    = smem + 2 * HIST_ELEMS;        // 4
    float* rowsum = smem + 2 * HIST_ELEMS + 4;    // 64
    float* colsum = smem + 2 * HIST_ELEMS + 68;   // 64
    float* colp   = smem + 2 * HIST_ELEMS + 132;  // 256
    float accl = 0.0f;
    for (int nn = 0; nn < 2; ++nn) {
        const float* h = smem + nn * HIST_ELEMS;
        {
            int r = tid >> 2, q = tid & 3;
            const float* hp = h + r * NBINS + q * 16;
            float sv = 0.0f;
            #pragma unroll
            for (int k = 0; k < 16; ++k) sv += hp[k];
            sv += __shfl_down(sv, 1, 64);
            sv += __shfl_down(sv, 2, 64);
            if (q == 0) rowsum[r] = sv;
        }
        {
            int c = tid & 63, g = tid >> 6;
            const float* hp = h + (g * 16) * NBINS + c;
            float sv = 0.0f;
            #pragma unroll
            for (int k = 0; k < 16; ++k) sv += hp[k * NBINS];
            colp[g * NBINS + c] = sv;
        }
        __syncthreads();
        if (tid < NBINS)
            colsum[tid] = colp[0 * NBINS + tid] + colp[1 * NBINS + tid] +
                          colp[2 * NBINS + tid] + colp[3 * NBINS + tid];
        __syncthreads();

        float tv = (tid < NBINS) ? rowsum[tid] : 0.0f;
        for (int off = 32; off > 0; off >>= 1) tv += __shfl_down(tv, off, 64);
        __syncthreads();
        if (lane == 0) buf[wave] = tv;
        __syncthreads();
        const float total = buf[0] + buf[1] + buf[2] + buf[3];
        const float inv = 1.0f / total;

        float ej = 0.0f;
        for (int i = tid; i < HIST_ELEMS; i += 256) {
            float p = h[i] * inv;
            ej += p * __logf(p + 1e-10f);
        }
        for (int off = 32; off > 0; off >>= 1) ej += __shfl_down(ej, off, 64);
        __syncthreads();
        if (lane == 0) buf[wave] = ej;
        __syncthreads();
        const float entj = -(buf[0] + buf[1] + buf[2] + buf[3]);

        float em = 0.0f;
        if (tid < NBINS) {
            float p = rowsum[tid] * inv;
            em = p * __logf(p + 1e-10f);
        } else if (tid < 2 * NBINS) {
            float p = colsum[tid - NBINS] * inv;
            em = p * __logf(p + 1e-10f);
        }
        for (int off = 32; off > 0; off >>= 1) em += __shfl_down(em, off, 64);
        __syncthreads();
        if (lane == 0) buf[wave] = em;
        __syncthreads();
        const float ents = -(buf[0] + buf[1] + buf[2] + buf[3]);

        accl += ents / entj;
        __syncthreads();
    }
    if (tid == 0) out[0] = -0.5f * accl;
}

extern "C" void kernel_launch(void* const* d_in, const int* in_sizes, int n_in,
                              void* d_out, int out_size, void* d_ws, size_t ws_size,
                              hipStream_t stream) {
    const float* tar = (const float*)d_in[0];
    const float* src = (const float*)d_in[1];
    const int N = 2;
    const int P = in_sizes[0] / N;  // 884736

    float* pm = (float*)d_ws;
    unsigned* ctr = (unsigned*)((char*)d_ws + 2048);
    float* histp = (float*)((char*)d_ws + 4096);
    float* out = (float*)d_out;

    minmax_kernel<<<dim3(64, N, 2), 256, 0, stream>>>(tar, src, pm, ctr, histp, P);
    mfma_hist_fused<<<dim3(GXN, N), 256, 0, stream>>>(tar, src, pm, ctr, histp, out, P);
}

// Round 12
// 132.984 us; speedup vs baseline: 1.0877x; 1.0877x over previous
//
#include <hip/hip_runtime.h>
#include <math.h>

#define NBINS 64
#define HIST_ELEMS (NBINS*NBINS)
#define PTS_PER_BLOCK 3456      // 256 blocks/n * 3456 = 884736 = P; grid 512 = 2/CU even
#define GXN 256                 // hist blocks per sample
#define CHUNKS 27               // per wave: 3456 / (4 waves * 32)
#define LSTRIDE 68              // col-major lh stride (b128 2-way banks = free)
// weight = exp2(-(u*SQK - b*SQK)^2); SQK = sqrt(8192/63^2*log2(e))
#define SQK 1.7256062f
#define SMEM_FLOATS (2*PTS_PER_BLOCK + NBINS*LSTRIDE)   // 11264 floats = 44 KB

typedef float f4 __attribute__((ext_vector_type(4)));
typedef float f32x4 __attribute__((ext_vector_type(4)));
typedef _Float16 half8 __attribute__((ext_vector_type(8)));
typedef int int4v __attribute__((ext_vector_type(4)));

static __device__ __forceinline__ half8 pack8(const float* w) {
    int4v v;
    v[0] = __builtin_bit_cast(int, __builtin_amdgcn_cvt_pkrtz(w[0], w[1]));
    v[1] = __builtin_bit_cast(int, __builtin_amdgcn_cvt_pkrtz(w[2], w[3]));
    v[2] = __builtin_bit_cast(int, __builtin_amdgcn_cvt_pkrtz(w[4], w[5]));
    v[3] = __builtin_bit_cast(int, __builtin_amdgcn_cvt_pkrtz(w[6], w[7]));
    return __builtin_bit_cast(half8, v);
}

// ws layout: pm[512] floats @0 | unsigned ctr @2048 | float hist[2][4096] @4096
//            | float bh[2*GXN][4096] @36864
__global__ __launch_bounds__(256) void minmax_kernel(const float* __restrict__ tar,
                                                     const float* __restrict__ src,
                                                     float* __restrict__ pm,
                                                     unsigned* __restrict__ ctr,
                                                     float* __restrict__ hist, int P) {
    const int b = blockIdx.x, n = blockIdx.y, t = blockIdx.z;
    const f4* x = (const f4*)((t == 0 ? tar : src) + (size_t)n * P);
    const int per = (P / 4) / 64;   // 3456 f4 per block
    float lmin = INFINITY, lmax = -INFINITY;
    for (int i = b * per + threadIdx.x; i < (b + 1) * per; i += 256) {
        f4 v = x[i];
        lmin = fminf(lmin, fminf(fminf(v[0], v[1]), fminf(v[2], v[3])));
        lmax = fmaxf(lmax, fmaxf(fmaxf(v[0], v[1]), fmaxf(v[2], v[3])));
    }
    for (int off = 32; off > 0; off >>= 1) {
        lmin = fminf(lmin, __shfl_down(lmin, off, 64));
        lmax = fmaxf(lmax, __shfl_down(lmax, off, 64));
    }
    __shared__ float smin[4], smax[4];
    const int lane = threadIdx.x & 63, wave = threadIdx.x >> 6;
    if (lane == 0) { smin[wave] = lmin; smax[wave] = lmax; }
    __syncthreads();
    if (threadIdx.x == 0) {
        pm[(n * 2 + t) * 64 + b] =
            fminf(fminf(smin[0], smin[1]), fminf(smin[2], smin[3]));
        pm[256 + (n * 2 + t) * 64 + b] =
            fmaxf(fmaxf(smax[0], smax[1]), fmaxf(smax[2], smax[3]));
    }
    // zero global hist (8192 floats over 256 blocks = 8 f4 each) + counter
    const int flat = b + 64 * n + 128 * t;   // 0..255
    f4* hz = (f4*)hist + flat * 8;
    const f4 z = {0.f, 0.f, 0.f, 0.f};
    if (threadIdx.x < 8) hz[threadIdx.x] = z;
    if (flat == 0 && threadIdx.x == 0) *ctr = 0u;
}

// Joint histogram as 64x64xP GEMM via MFMA f16 (R9 core).  Wave 0 reduces the
// 64 per-block minmax partials inline; one staging phase; 27 barrier-free
// K=32 chunks/wave; serial-wave NON-ATOMIC combine; private bh tile stores
// (no global atomics, no fences -- the R10/R11 atomic flush cost ~35us).
// A[m][k]: m=lane&15 (+16*mt), k=quad*8+j ; B[k][n]: n=lane&15, k=quad*8+j
// C/D: col=lane&15, row=quad*4+reg -> col-major lh; output TRANSPOSED
// (MI loss is transpose-invariant).
template <int STAGED>
__global__ __launch_bounds__(256) void mfma_hist_kernel(const float* __restrict__ tar,
                                                        const float* __restrict__ src,
                                                        const float* __restrict__ pm,
                                                        float* __restrict__ bh,
                                                        float* __restrict__ hist,
                                                        int P) {
    const int n = blockIdx.y;
    const int bx = blockIdx.x;
    const int tid = threadIdx.x;
    const int lane = tid & 63, wave = tid >> 6;
    const int mlane = lane & 15, quad = lane >> 4;

    __shared__ float smem[SMEM_FLOATS];
    __shared__ float mmred[4];
    float* su_t = smem;
    float* su_s = smem + PTS_PER_BLOCK;
    float* lh = smem + 2 * PTS_PER_BLOCK;   // col-major: lh[col*LSTRIDE + row]

    // --- wave 0: reduce the 64 per-block minmax partials ---
    if (wave == 0) {
        float a = pm[(n * 2 + 0) * 64 + lane];
        float b = pm[256 + (n * 2 + 0) * 64 + lane];
        float c = pm[(n * 2 + 1) * 64 + lane];
        float d = pm[256 + (n * 2 + 1) * 64 + lane];
        for (int off = 32; off > 0; off >>= 1) {
            a = fminf(a, __shfl_down(a, off, 64));
            b = fmaxf(b, __shfl_down(b, off, 64));
            c = fminf(c, __shfl_down(c, off, 64));
            d = fmaxf(d, __shfl_down(d, off, 64));
        }
        if (lane == 0) { mmred[0] = a; mmred[1] = b; mmred[2] = c; mmred[3] = d; }
    }

    // --- stage raw inputs: 864 f4 per tensor, coalesced ---
    {
        const f4* tg = (const f4*)(tar + (size_t)n * P + (size_t)bx * PTS_PER_BLOCK);
        const f4* sg = (const f4*)(src + (size_t)n * P + (size_t)bx * PTS_PER_BLOCK);
        f4* st4 = (f4*)su_t;
        f4* ss4 = (f4*)su_s;
        #pragma unroll
        for (int k = 0; k < 3; ++k) {
            const int i = tid + k * 256;
            st4[i] = tg[i];
            ss4[i] = sg[i];
        }
        if (tid < 96) {
            const int i = 768 + tid;
            st4[i] = tg[i];
            ss4[i] = sg[i];
        }
    }
    __syncthreads();   // staging + mmred complete

    const float tmin = mmred[0], tmax = mmred[1];
    const float smin = mmred[2], smax = mmred[3];
    const float tk = 63.0f / (tmax - tmin + 1e-10f) * SQK;
    const float sk = 63.0f / (smax - smin + 1e-10f) * SQK;
    float mt2[4], ms2[4];
    #pragma unroll
    for (int mt = 0; mt < 4; ++mt) {
        const float b = SQK * (float)(mlane + 16 * mt);
        mt2[mt] = tmin * tk + b;
        ms2[mt] = smin * sk + b;
    }

    f32x4 acc[4][4];
    #pragma unroll
    for (int a = 0; a < 4; ++a)
        #pragma unroll
        for (int b = 0; b < 4; ++b) acc[a][b] = (f32x4){0.f, 0.f, 0.f, 0.f};

    // --- compute: wave owns 864 points = 27 chunks of K=32, barrier-free ---
    const int kwbase = wave * (32 * CHUNKS) + quad * 8;
    #pragma unroll 3
    for (int c = 0; c < CHUNKS; ++c) {
        const int kbase = kwbase + c * 32;
        const f4* pt4 = (const f4*)&su_t[kbase];
        const f4* ps4 = (const f4*)&su_s[kbase];
        f4 ta = pt4[0], tb = pt4[1];
        f4 sa = ps4[0], sb = ps4[1];
        float xt[8] = {ta[0], ta[1], ta[2], ta[3], tb[0], tb[1], tb[2], tb[3]};
        float xs[8] = {sa[0], sa[1], sa[2], sa[3], sb[0], sb[1], sb[2], sb[3]};

        half8 af[4], bf[4];
        #pragma unroll
        for (int mt = 0; mt < 4; ++mt) {
            float w[8];
            #pragma unroll
            for (int j = 0; j < 8; ++j) {
                float d = fmaf(xt[j], tk, -mt2[mt]);
                w[j] = __builtin_amdgcn_exp2f(-(d * d));
            }
            af[mt] = pack8(w);
        }
        #pragma unroll
        for (int nt = 0; nt < 4; ++nt) {
            float w[8];
            #pragma unroll
            for (int j = 0; j < 8; ++j) {
                float d = fmaf(xs[j], sk, -ms2[nt]);
                w[j] = __builtin_amdgcn_exp2f(-(d * d));
            }
            bf[nt] = pack8(w);
        }
        #pragma unroll
        for (int mt = 0; mt < 4; ++mt)
            #pragma unroll
            for (int nt = 0; nt < 4; ++nt)
                acc[mt][nt] = __builtin_amdgcn_mfma_f32_16x16x32_f16(
                    af[mt], bf[nt], acc[mt][nt], 0, 0, 0);
    }

    // --- serial-wave non-atomic combine into col-major lh ---
    #pragma unroll
    for (int w = 0; w < 4; ++w) {
        if (wave == w) {
            #pragma unroll
            for (int nt = 0; nt < 4; ++nt)
                #pragma unroll
                for (int mt = 0; mt < 4; ++mt) {
                    f4* p = (f4*)&lh[(16 * nt + mlane) * LSTRIDE + 16 * mt + 4 * quad];
                    if (w == 0) {
                        *p = acc[mt][nt];
                    } else {
                        f4 v = *p;
                        v += acc[mt][nt];
                        *p = v;
                    }
                }
        }
        __syncthreads();
    }

    if (STAGED) {
        // compact col-major lh -> private dense 4096-float tile (no atomics)
        f4* dst = (f4*)(bh + ((size_t)n * GXN + bx) * HIST_ELEMS);
        #pragma unroll
        for (int k = 0; k < 4; ++k) {
            const int i4 = tid + k * 256;          // 0..1023
            const int c = i4 >> 4, r4 = (i4 & 15) * 4;
            dst[i4] = *(const f4*)&lh[c * LSTRIDE + r4];
        }
    } else {
        float* gh = hist + (size_t)n * HIST_ELEMS;
        for (int i = tid; i < HIST_ELEMS; i += 256) {
            const int c = i >> 6, r = i & 63;
            unsafeAtomicAdd(&gh[i], lh[c * LSTRIDE + r]);
        }
    }
}

// 32 blocks: sum bh tiles -> hist (plain stores), then last block finalizes.
__global__ __launch_bounds__(256) void reduce_finalize_kernel(const float* __restrict__ bh,
                                                              float* __restrict__ hist,
                                                              unsigned* __restrict__ ctr,
                                                              float* __restrict__ out,
                                                              int staged) {
    const int tid = threadIdx.x;
    const int lane = tid & 63, wave = tid >> 6;
    __shared__ float h2[2 * HIST_ELEMS];
    __shared__ float buf[4], rowsum[NBINS], colsum[NBINS], colp[4 * NBINS];
    __shared__ int lastflag;

    if (staged) {
        const int g = blockIdx.x * 256 + tid;   // 0..8191
        const int n = g >> 12, e = g & 4095;
        const float* p = bh + (((size_t)n * GXN) << 12) + e;
        float sum = 0.0f;
        #pragma unroll 8
        for (int b = 0; b < GXN; ++b) sum += p[(size_t)b << 12];
        hist[g] = sum;
    }

    __threadfence();
    if (tid == 0) {
        unsigned old = atomicAdd(ctr, 1u);
        lastflag = (old == 31) ? 1 : 0;
    }
    __syncthreads();
    if (!lastflag) return;

    // system-scope loads: bypass per-XCD L2 (writers fenced via threadfence)
    for (int i = tid; i < 2 * HIST_ELEMS; i += 256)
        h2[i] = __hip_atomic_load(&hist[i], __ATOMIC_RELAXED, __HIP_MEMORY_SCOPE_SYSTEM);
    __syncthreads();

    float accl = 0.0f;
    for (int nn = 0; nn < 2; ++nn) {
        const float* h = h2 + nn * HIST_ELEMS;
        {
            int r = tid >> 2, q = tid & 3;
            const float* hp = h + r * NBINS + q * 16;
            float sv = 0.0f;
            #pragma unroll
            for (int k = 0; k < 16; ++k) sv += hp[k];
            sv += __shfl_down(sv, 1, 64);
            sv += __shfl_down(sv, 2, 64);
            if (q == 0) rowsum[r] = sv;
        }
        {
            int c = tid & 63, g = tid >> 6;
            const float* hp = h + (g * 16) * NBINS + c;
            float sv = 0.0f;
            #pragma unroll
            for (int k = 0; k < 16; ++k) sv += hp[k * NBINS];
            colp[g * NBINS + c] = sv;
        }
        __syncthreads();
        if (tid < NBINS)
            colsum[tid] = colp[0 * NBINS + tid] + colp[1 * NBINS + tid] +
                          colp[2 * NBINS + tid] + colp[3 * NBINS + tid];
        __syncthreads();

        float tv = (tid < NBINS) ? rowsum[tid] : 0.0f;
        for (int off = 32; off > 0; off >>= 1) tv += __shfl_down(tv, off, 64);
        __syncthreads();
        if (lane == 0) buf[wave] = tv;
        __syncthreads();
        const float total = buf[0] + buf[1] + buf[2] + buf[3];
        const float inv = 1.0f / total;

        float ej = 0.0f;
        for (int i = tid; i < HIST_ELEMS; i += 256) {
            float p = h[i] * inv;
            ej += p * __logf(p + 1e-10f);
        }
        for (int off = 32; off > 0; off >>= 1) ej += __shfl_down(ej, off, 64);
        __syncthreads();
        if (lane == 0) buf[wave] = ej;
        __syncthreads();
        const float entj = -(buf[0] + buf[1] + buf[2] + buf[3]);

        float em = 0.0f;
        if (tid < NBINS) {
            float p = rowsum[tid] * inv;
            em = p * __logf(p + 1e-10f);
        } else if (tid < 2 * NBINS) {
            float p = colsum[tid - NBINS] * inv;
            em = p * __logf(p + 1e-10f);
        }
        for (int off = 32; off > 0; off >>= 1) em += __shfl_down(em, off, 64);
        __syncthreads();
        if (lane == 0) buf[wave] = em;
        __syncthreads();
        const float ents = -(buf[0] + buf[1] + buf[2] + buf[3]);

        accl += ents / entj;
        __syncthreads();
    }
    if (tid == 0) out[0] = -0.5f * accl;
}

extern "C" void kernel_launch(void* const* d_in, const int* in_sizes, int n_in,
                              void* d_out, int out_size, void* d_ws, size_t ws_size,
                              hipStream_t stream) {
    const float* tar = (const float*)d_in[0];
    const float* src = (const float*)d_in[1];
    const int N = 2;
    const int P = in_sizes[0] / N;  // 884736

    float* pm = (float*)d_ws;
    unsigned* ctr = (unsigned*)((char*)d_ws + 2048);
    float* hist = (float*)((char*)d_ws + 4096);
    float* bh = (float*)((char*)d_ws + 36864);
    float* out = (float*)d_out;

    const size_t need = 36864 + (size_t)2 * GXN * HIST_ELEMS * 4;   // ~8.4 MB

    minmax_kernel<<<dim3(64, N, 2), 256, 0, stream>>>(tar, src, pm, ctr, hist, P);
    if (ws_size >= need) {
        mfma_hist_kernel<1><<<dim3(GXN, N), 256, 0, stream>>>(tar, src, pm, bh, hist, P);
        reduce_finalize_kernel<<<32, 256, 0, stream>>>(bh, hist, ctr, out, 1);
    } else {
        mfma_hist_kernel<0><<<dim3(GXN, N), 256, 0, stream>>>(tar, src, pm, bh, hist, P);
        reduce_finalize_kernel<<<32, 256, 0, stream>>>(bh, hist, ctr, out, 0);
    }
}